// Round 11
// baseline (106.478 us; speedup 1.0000x reference)
//
#include <hip/hip_runtime.h>
#include <math.h>

#define Bq 8
#define Qq 256
#define Tt 128
#define Pp 100
#define Mm 512
#define Nn 1024  // B*T

// Block-wide sum over 256 threads (4 waves of 64). Result broadcast to all threads.
__device__ __forceinline__ float breduce256(float v, float* red) {
    #pragma unroll
    for (int off = 32; off > 0; off >>= 1) v += __shfl_down(v, off, 64);
    __syncthreads();                         // protect red[] reuse across calls
    if ((threadIdx.x & 63) == 0) red[threadIdx.x >> 6] = v;
    __syncthreads();
    return red[0] + red[1] + red[2] + red[3];
}

// One v_min against a DPP-permuted copy (VALU pipe — no LDS traffic).
template<int CTRL>
__device__ __forceinline__ float dpp_min_step(float v) {
    const int x = __builtin_amdgcn_update_dpp(0, __float_as_int(v), CTRL, 0xF, 0xF, true);
    return fminf(v, __int_as_float(x));
}
// Min across a row of 16 lanes: xor1, xor2 (quad_perm), then ror4 + ror8.
__device__ __forceinline__ float row16_min(float v) {
    v = dpp_min_step<0xB1>(v);   // quad_perm [1,0,3,2]
    v = dpp_min_step<0x4E>(v);   // quad_perm [2,3,0,1]
    v = dpp_min_step<0x124>(v);  // row_ror:4
    v = dpp_min_step<0x128>(v);  // row_ror:8
    return v;
}

// One block per patch. ZERO LDS in the hot loop (r3-r9 all bottlenecked on the
// per-CU DS pipe: reads+atomics+staging, 8-way conflicted). New dataflow:
//  - tgt points read from GLOBAL (L1/L2 broadcast): 16 lanes of chunk C share
//    point 32C+j; 3 scalar loads/iter; tgt streamed once per block (6 KB).
//  - src points (8/lane) read from global into 24 NAMED registers, pinned with
//    empty inline asm so the allocator can't rematerialize them into the loop.
//    pbase=min(8g,92): lanes g>=12 hold duplicate points (dupes are harmless
//    for min in both passes) -> no OOB, no sentinels, no predication.
//  - pass A (min over p per m): per-lane tree min + 4-step DPP row-16
//    butterfly (VALU pipe); every lane accumulates sumA (/16 dup at end).
//  - pass B (min over m per p): per-lane register mins, combined once at loop
//    end via shfl_xor(16,32) + 512 one-time LDS atomicMin.
// The LAST block to finish (device-scope counter) computes the classification
// losses inline -> single dispatch.
__global__ __launch_bounds__(256, 4) void fused_kernel(
    const float* __restrict__ logits,     // [B,Q,2]
    const float* __restrict__ pred_pts,   // [B,Q,P,3]
    const float* __restrict__ tgt_pts,    // [B,T,M,3]
    const int*   __restrict__ src_idx,    // [B,T]
    float*       __restrict__ per_patch,  // ws: [N]
    unsigned*    __restrict__ done_ctr,   // ws+4096, zeroed per launch
    float*       __restrict__ out)        // [5]
{
    __shared__ unsigned s_bmin[128];      // per-p min over m
    __shared__ float    red[4];
    __shared__ unsigned s_lastflag;
    const int n   = blockIdx.x;
    const int tid = threadIdx.x;
    const int b   = n >> 7;               // n / T
    const int q   = src_idx[n];
    const float* sp = pred_pts + (size_t)(b * Qq + q) * (Pp * 3);
    const float* tp = tgt_pts  + (size_t)n * (Mm * 3);

    if (tid < 128) s_bmin[tid] = 0x7f7fffffu;

    const int g     = tid & 15;           // src sub-block (8 points)
    const int C     = tid >> 4;           // m-chunk 0..15 (32 m's each)
    const int pbase = (g < 12) ? 8 * g : 92;   // clamp: g=12 -> p 92..99

    // 8 src points = 24 floats via 6 aligned float4 global loads.
    const float4* s4 = (const float4*)(sp + pbase * 3);
    const float4 v0 = s4[0], v1 = s4[1], v2 = s4[2],
                 v3 = s4[3], v4 = s4[4], v5 = s4[5];
    float s0x=v0.x, s0y=v0.y, s0z=v0.z;
    float s1x=v0.w, s1y=v1.x, s1z=v1.y;
    float s2x=v1.z, s2y=v1.w, s2z=v2.x;
    float s3x=v2.y, s3y=v2.z, s3z=v2.w;
    float s4x=v3.x, s4y=v3.y, s4z=v3.z;
    float s5x=v3.w, s5y=v4.x, s5z=v4.y;
    float s6x=v4.z, s6y=v4.w, s6z=v5.x;
    float s7x=v5.y, s7y=v5.z, s7z=v5.w;
    // Pin all 24 to VGPRs: opaque asm def -> not rematerializable.
    asm volatile("" : "+v"(s0x),"+v"(s0y),"+v"(s0z),"+v"(s1x),"+v"(s1y),"+v"(s1z),
                      "+v"(s2x),"+v"(s2y),"+v"(s2z),"+v"(s3x),"+v"(s3y),"+v"(s3z),
                      "+v"(s4x),"+v"(s4y),"+v"(s4z),"+v"(s5x),"+v"(s5y),"+v"(s5z),
                      "+v"(s6x),"+v"(s6y),"+v"(s6z),"+v"(s7x),"+v"(s7y),"+v"(s7z));

    float mn0 = 3.4e38f, mn1 = 3.4e38f, mn2 = 3.4e38f, mn3 = 3.4e38f;
    float mn4 = 3.4e38f, mn5 = 3.4e38f, mn6 = 3.4e38f, mn7 = 3.4e38f;
    float sumA = 0.f;
    const float* tbase = tp + C * 96;     // chunk C: points 32C..32C+31

    #pragma unroll 4
    for (int j = 0; j < 32; ++j) {
        const float tx = tbase[3*j+0], ty = tbase[3*j+1], tz = tbase[3*j+2];
        float dx, dy, dz;
        dx = s0x-tx; dy = s0y-ty; dz = s0z-tz;
        const float d0 = fmaf(dx,dx,fmaf(dy,dy,dz*dz)); mn0 = fminf(mn0,d0);
        dx = s1x-tx; dy = s1y-ty; dz = s1z-tz;
        const float d1 = fmaf(dx,dx,fmaf(dy,dy,dz*dz)); mn1 = fminf(mn1,d1);
        dx = s2x-tx; dy = s2y-ty; dz = s2z-tz;
        const float d2 = fmaf(dx,dx,fmaf(dy,dy,dz*dz)); mn2 = fminf(mn2,d2);
        dx = s3x-tx; dy = s3y-ty; dz = s3z-tz;
        const float d3 = fmaf(dx,dx,fmaf(dy,dy,dz*dz)); mn3 = fminf(mn3,d3);
        dx = s4x-tx; dy = s4y-ty; dz = s4z-tz;
        const float d4 = fmaf(dx,dx,fmaf(dy,dy,dz*dz)); mn4 = fminf(mn4,d4);
        dx = s5x-tx; dy = s5y-ty; dz = s5z-tz;
        const float d5 = fmaf(dx,dx,fmaf(dy,dy,dz*dz)); mn5 = fminf(mn5,d5);
        dx = s6x-tx; dy = s6y-ty; dz = s6z-tz;
        const float d6 = fmaf(dx,dx,fmaf(dy,dy,dz*dz)); mn6 = fminf(mn6,d6);
        dx = s7x-tx; dy = s7y-ty; dz = s7z-tz;
        const float d7 = fmaf(dx,dx,fmaf(dy,dy,dz*dz)); mn7 = fminf(mn7,d7);
        float pm = fminf(fminf(fminf(d0,d1), fminf(d2,d3)),
                         fminf(fminf(d4,d5), fminf(d6,d7)));
        pm = row16_min(pm);               // min over all 128 p (16 lanes x 8)
        sumA += pm;                       // all 16 lanes add (dup /16 later)
    }

    // Pass B combine: min across the wave's 4 chunk-rows (same g, cc 0..3).
    mn0 = fminf(mn0, __shfl_xor(mn0,16,64)); mn0 = fminf(mn0, __shfl_xor(mn0,32,64));
    mn1 = fminf(mn1, __shfl_xor(mn1,16,64)); mn1 = fminf(mn1, __shfl_xor(mn1,32,64));
    mn2 = fminf(mn2, __shfl_xor(mn2,16,64)); mn2 = fminf(mn2, __shfl_xor(mn2,32,64));
    mn3 = fminf(mn3, __shfl_xor(mn3,16,64)); mn3 = fminf(mn3, __shfl_xor(mn3,32,64));
    mn4 = fminf(mn4, __shfl_xor(mn4,16,64)); mn4 = fminf(mn4, __shfl_xor(mn4,32,64));
    mn5 = fminf(mn5, __shfl_xor(mn5,16,64)); mn5 = fminf(mn5, __shfl_xor(mn5,32,64));
    mn6 = fminf(mn6, __shfl_xor(mn6,16,64)); mn6 = fminf(mn6, __shfl_xor(mn6,32,64));
    mn7 = fminf(mn7, __shfl_xor(mn7,16,64)); mn7 = fminf(mn7, __shfl_xor(mn7,32,64));
    __syncthreads();                      // s_bmin init visible to all
    if (((tid >> 4) & 3) == 0) {          // one lane-row per wave writes
        atomicMin(&s_bmin[pbase+0], __float_as_uint(mn0));
        atomicMin(&s_bmin[pbase+1], __float_as_uint(mn1));
        atomicMin(&s_bmin[pbase+2], __float_as_uint(mn2));
        atomicMin(&s_bmin[pbase+3], __float_as_uint(mn3));
        atomicMin(&s_bmin[pbase+4], __float_as_uint(mn4));
        atomicMin(&s_bmin[pbase+5], __float_as_uint(mn5));
        atomicMin(&s_bmin[pbase+6], __float_as_uint(mn6));
        atomicMin(&s_bmin[pbase+7], __float_as_uint(mn7));
    }
    __syncthreads();

    float contrib = sumA * (1.0f / (16.0f * Mm));      // /16 lane-duplication
    if (tid < Pp) contrib += 0.2f * __uint_as_float(s_bmin[tid]) * (1.0f / Pp);

    const float tot = breduce256(contrib, red);
    if (tid == 0) {
        per_patch[n] = tot * (1.0f / 1.2f);
        __threadfence();                                   // publish before count
        s_lastflag = (atomicAdd(done_ctr, 1u) == (unsigned)(Nn - 1));
    }
    __syncthreads();
    if (!s_lastflag) return;

    // ---------------- consumer tail: classification losses (one block) -------
    __shared__ unsigned char matched[Bq * Qq];
    __shared__ int s_card[Bq];
    for (int i = tid; i < Bq * Qq; i += 256) matched[i] = 0;
    if (tid < Bq) s_card[tid] = 0;
    __syncthreads();
    for (int i = tid; i < Nn; i += 256) matched[(i >> 7) * Qq + src_idx[i]] = 1;
    __syncthreads();

    float sum_nll = 0.f, sum_wt = 0.f, cnt_ov = 0.f;
    #pragma unroll
    for (int k = 0; k < 8; ++k) {                // k == batch b (Q == 256)
        const int i = tid + (k << 8);
        const float2 l = ((const float2*)logits)[i];
        const int mt = matched[i];
        const float mx  = fmaxf(l.x, l.y);
        const float lse = mx + logf(expf(l.x - mx) + expf(l.y - mx));
        sum_nll += (mt ? 1.0f : 0.1f) * (lse - (mt ? l.x : l.y));
        sum_wt  += mt ? 1.0f : 0.1f;
        const int pred0 = (l.x >= l.y) ? 1 : 0;  // argmax==0 (tie -> first)
        cnt_ov += (pred0 == mt) ? 1.f : 0.f;
        const unsigned long long bal = __ballot(pred0);
        if ((tid & 63) == 0) atomicAdd(&s_card[k], (int)__popcll(bal));
    }
    float cnt_va = 0.f, gsum = 0.f;
    const volatile float* vpp = per_patch;       // cross-XCD: bypass reg caching
    for (int i = tid; i < Nn; i += 256) {
        const float2 l = ((const float2*)logits)[(i >> 7) * Qq + src_idx[i]];
        cnt_va += (l.x >= l.y) ? 1.f : 0.f;
        gsum   += vpp[i];
    }

    const float t_nll = breduce256(sum_nll, red);
    const float t_wt  = breduce256(sum_wt,  red);
    const float t_ov  = breduce256(cnt_ov,  red);
    const float t_va  = breduce256(cnt_va,  red);
    const float t_gs  = breduce256(gsum,    red);

    if (tid == 0) {
        float cerr = 0.f;
        for (int bb = 0; bb < Bq; ++bb) cerr += fabsf((float)s_card[bb] - (float)Tt);
        out[0] = t_nll / t_wt;
        out[1] = 100.f * t_va / (float)Nn;
        out[2] = 100.f * t_ov / (float)(Bq * Qq);
        out[3] = cerr / (float)Bq;
        out[4] = t_gs / (float)Nn;
    }
}

extern "C" void kernel_launch(void* const* d_in, const int* in_sizes, int n_in,
                              void* d_out, int out_size, void* d_ws, size_t ws_size,
                              hipStream_t stream) {
    const float* logits   = (const float*)d_in[0];  // [B,Q,2]
    const float* pred_pts = (const float*)d_in[1];  // [B,Q,P,3]
    const float* tgt_pts  = (const float*)d_in[2];  // [B,T,M,3]
    const int*   src_idx  = (const int*)  d_in[3];  // [B,T]
    float* out       = (float*)d_out;               // 5 scalars
    float* per_patch = (float*)d_ws;                // [1024] floats
    unsigned* ctr    = (unsigned*)((char*)d_ws + 4096);

    hipMemsetAsync(ctr, 0, sizeof(unsigned), stream);   // graph-capture legal
    fused_kernel<<<Nn, 256, 0, stream>>>(logits, pred_pts, tgt_pts, src_idx,
                                         per_patch, ctr, out);
}

// Round 13
// 100.293 us; speedup vs baseline: 1.0617x; 1.0617x over previous
//
#include <hip/hip_runtime.h>
#include <math.h>

#define Bq 8
#define Qq 256
#define Tt 128
#define Pp 100
#define Mm 512
#define Nn 1024  // B*T

// Block-wide sum over 256 threads (4 waves of 64). Result broadcast to all threads.
__device__ __forceinline__ float breduce256(float v, float* red) {
    #pragma unroll
    for (int off = 32; off > 0; off >>= 1) v += __shfl_down(v, off, 64);
    __syncthreads();                         // protect red[] reuse across calls
    if ((threadIdx.x & 63) == 0) red[threadIdx.x >> 6] = v;
    __syncthreads();
    return red[0] + red[1] + red[2] + red[3];
}

// One block per patch. This is round-5's geometry hot loop VERBATIM (the
// empirically fastest variant, ~21 us: 4-src-pt implicit register tile,
// 64 rotated ds_read_b128 + 64 LDS atomicMin, s_bpart combine — no asm pins,
// no launch_bounds minimum; every attempted "improvement" on it regressed
// 2-2.7x), plus round-6's proven-correct last-block classification tail
// (device-scope counter; saves the second dispatch + launch gap).
__global__ __launch_bounds__(256) void fused_kernel(
    const float* __restrict__ logits,     // [B,Q,2]
    const float* __restrict__ pred_pts,   // [B,Q,P,3]
    const float* __restrict__ tgt_pts,    // [B,T,M,3]
    const int*   __restrict__ src_idx,    // [B,T]
    float*       __restrict__ per_patch,  // ws: [N]
    unsigned*    __restrict__ done_ctr,   // ws+4096, zeroed per launch
    float*       __restrict__ out)        // [5]
{
    __shared__ float4   s_tgt[Mm];        // 8 KB
    __shared__ float4   s_src[128];       // 2 KB (padded)
    __shared__ unsigned s_amin[Mm];       // 2 KB: per-m min over p (as uint)
    __shared__ float    s_bpart[8][128];  // 4 KB: per-chunk per-p partial mins
    __shared__ float    red[4];
    __shared__ unsigned s_lastflag;
    const int n   = blockIdx.x;
    const int tid = threadIdx.x;
    const int b   = n >> 7;               // n / T
    const int q   = src_idx[n];
    const float* sp = pred_pts + (size_t)(b * Qq + q) * (Pp * 3);
    const float* tp = tgt_pts  + (size_t)n * (Mm * 3);

    // Stage tgt: 512 pts x 3 floats = 768 float2; thread repacks 2 points.
    {
        const float2* tp2 = (const float2*)tp;
        const float2 a = tp2[3*tid], c2 = tp2[3*tid+1], e = tp2[3*tid+2];
        s_tgt[2*tid]   = make_float4(a.x, a.y, c2.x, 0.f);
        s_tgt[2*tid+1] = make_float4(c2.y, e.x, e.y, 0.f);
    }
    // Stage src: threads 0..49 repack 2 points each; 100..127 write sentinels.
    if (tid < 50) {
        const float2* sp2 = (const float2*)sp;
        const float2 a = sp2[3*tid], c2 = sp2[3*tid+1], e = sp2[3*tid+2];
        s_src[2*tid]   = make_float4(a.x, a.y, c2.x, 0.f);
        s_src[2*tid+1] = make_float4(c2.y, e.x, e.y, 0.f);
    } else if (tid >= 100 && tid < 128) {
        s_src[tid] = make_float4(5e18f, 5e18f, 5e18f, 0.f);
    }
    // Init per-m min array (uint encoding of FLT_MAX).
    *(uint2*)&s_amin[2*tid] = make_uint2(0x7f7fffffu, 0x7f7fffffu);
    __syncthreads();

    const int g = tid & 31;
    const int c = tid >> 5;               // m-chunk 0..7
    const int mbase = c << 6;
    const float4 s0 = s_src[4*g+0], s1 = s_src[4*g+1],
                 s2 = s_src[4*g+2], s3 = s_src[4*g+3];
    float mn0 = 3.4e38f, mn1 = 3.4e38f, mn2 = 3.4e38f, mn3 = 3.4e38f;

    #pragma unroll 4
    for (int j = 0; j < 64; ++j) {
        const int m = mbase + ((j + g) & 63);   // rotate: distinct addr per lane
        const float4 t = s_tgt[m];
        float dx, dy, dz;
        dx = s0.x - t.x; dy = s0.y - t.y; dz = s0.z - t.z;
        const float d0 = fmaf(dx, dx, fmaf(dy, dy, dz * dz));
        dx = s1.x - t.x; dy = s1.y - t.y; dz = s1.z - t.z;
        const float d1 = fmaf(dx, dx, fmaf(dy, dy, dz * dz));
        dx = s2.x - t.x; dy = s2.y - t.y; dz = s2.z - t.z;
        const float d2 = fmaf(dx, dx, fmaf(dy, dy, dz * dz));
        dx = s3.x - t.x; dy = s3.y - t.y; dz = s3.z - t.z;
        const float d3 = fmaf(dx, dx, fmaf(dy, dy, dz * dz));
        mn0 = fminf(mn0, d0); mn1 = fminf(mn1, d1);
        mn2 = fminf(mn2, d2); mn3 = fminf(mn3, d3);
        const float pm = fminf(fminf(d0, d1), fminf(d2, d3));
        atomicMin(&s_amin[m], __float_as_uint(pm));   // nonneg: uint cmp == float cmp
    }

    // Per-p partials for this chunk -> LDS (contiguous 4 floats = one b128).
    *(float4*)&s_bpart[c][4*g] = make_float4(mn0, mn1, mn2, mn3);
    __syncthreads();

    float contrib;
    // Pass A: mean over m of min_p. Thread sums its 2 m-slots.
    {
        const uint2 u = *(const uint2*)&s_amin[2*tid];
        contrib = (__uint_as_float(u.x) + __uint_as_float(u.y)) * (1.0f / Mm);
    }
    // Pass B: combine the 8 chunk-partials; threads 0..99 own one p each.
    if (tid < Pp) {
        float mn = s_bpart[0][tid];
        #pragma unroll
        for (int cc = 1; cc < 8; ++cc) mn = fminf(mn, s_bpart[cc][tid]);
        contrib += 0.2f * mn * (1.0f / Pp);
    }

    const float tot = breduce256(contrib, red);
    if (tid == 0) {
        per_patch[n] = tot * (1.0f / 1.2f);
        __threadfence();                                   // publish before count
        s_lastflag = (atomicAdd(done_ctr, 1u) == (unsigned)(Nn - 1));
    }
    __syncthreads();
    if (!s_lastflag) return;

    // ---------------- consumer tail: classification losses (one block) -------
    __shared__ unsigned char matched[Bq * Qq];
    __shared__ int s_card[Bq];
    for (int i = tid; i < Bq * Qq; i += 256) matched[i] = 0;
    if (tid < Bq) s_card[tid] = 0;
    __syncthreads();
    for (int i = tid; i < Nn; i += 256) matched[(i >> 7) * Qq + src_idx[i]] = 1;
    __syncthreads();

    float sum_nll = 0.f, sum_wt = 0.f, cnt_ov = 0.f;
    #pragma unroll
    for (int k = 0; k < 8; ++k) {                // k == batch b (Q == 256)
        const int i = tid + (k << 8);
        const float2 l = ((const float2*)logits)[i];
        const int mt = matched[i];
        const float mx  = fmaxf(l.x, l.y);
        const float lse = mx + logf(expf(l.x - mx) + expf(l.y - mx));
        sum_nll += (mt ? 1.0f : 0.1f) * (lse - (mt ? l.x : l.y));
        sum_wt  += mt ? 1.0f : 0.1f;
        const int pred0 = (l.x >= l.y) ? 1 : 0;  // argmax==0 (tie -> first)
        cnt_ov += (pred0 == mt) ? 1.f : 0.f;
        const unsigned long long bal = __ballot(pred0);
        if ((tid & 63) == 0) atomicAdd(&s_card[k], (int)__popcll(bal));
    }
    float cnt_va = 0.f, gsum = 0.f;
    const volatile float* vpp = per_patch;       // cross-XCD: bypass reg caching
    for (int i = tid; i < Nn; i += 256) {
        const float2 l = ((const float2*)logits)[(i >> 7) * Qq + src_idx[i]];
        cnt_va += (l.x >= l.y) ? 1.f : 0.f;
        gsum   += vpp[i];
    }

    const float t_nll = breduce256(sum_nll, red);
    const float t_wt  = breduce256(sum_wt,  red);
    const float t_ov  = breduce256(cnt_ov,  red);
    const float t_va  = breduce256(cnt_va,  red);
    const float t_gs  = breduce256(gsum,    red);

    if (tid == 0) {
        float cerr = 0.f;
        for (int bb = 0; bb < Bq; ++bb) cerr += fabsf((float)s_card[bb] - (float)Tt);
        out[0] = t_nll / t_wt;
        out[1] = 100.f * t_va / (float)Nn;
        out[2] = 100.f * t_ov / (float)(Bq * Qq);
        out[3] = cerr / (float)Bq;
        out[4] = t_gs / (float)Nn;
    }
}

extern "C" void kernel_launch(void* const* d_in, const int* in_sizes, int n_in,
                              void* d_out, int out_size, void* d_ws, size_t ws_size,
                              hipStream_t stream) {
    const float* logits   = (const float*)d_in[0];  // [B,Q,2]
    const float* pred_pts = (const float*)d_in[1];  // [B,Q,P,3]
    const float* tgt_pts  = (const float*)d_in[2];  // [B,T,M,3]
    const int*   src_idx  = (const int*)  d_in[3];  // [B,T]
    float* out       = (float*)d_out;               // 5 scalars
    float* per_patch = (float*)d_ws;                // [1024] floats
    unsigned* ctr    = (unsigned*)((char*)d_ws + 4096);

    hipMemsetAsync(ctr, 0, sizeof(unsigned), stream);   // graph-capture legal
    fused_kernel<<<Nn, 256, 0, stream>>>(logits, pred_pts, tgt_pts, src_idx,
                                         per_patch, ctr, out);
}

// Round 17
// 86.337 us; speedup vs baseline: 1.2333x; 1.1616x over previous
//
#include <hip/hip_runtime.h>
#include <math.h>

#define Bq 8
#define Qq 256
#define Tt 128
#define Pp 100
#define Mm 512
#define Nn 1024  // B*T

// Block-wide sum over 256 threads (4 waves of 64). Result broadcast to all threads.
__device__ __forceinline__ float breduce256(float v, float* red) {
    #pragma unroll
    for (int off = 32; off > 0; off >>= 1) v += __shfl_down(v, off, 64);
    __syncthreads();                         // protect red[] reuse across calls
    if ((threadIdx.x & 63) == 0) red[threadIdx.x >> 6] = v;
    __syncthreads();
    return red[0] + red[1] + red[2] + red[3];
}

// One block per patch. FUSED single-pass chamfer: each distance computed ONCE.
// Thread (c = tid>>5, g = tid&31) holds src points p = 4g..4g+3 in REGISTERS
// and sweeps tgt chunk m in [64c, 64c+64). Empirically the fastest structure
// tried (r5: ~20.5 us); all restructures (bigger tiles, asm pins, zero-LDS
// DPP, last-block fusion) regressed 2-2.7x via compiler regalloc pathologies.
__global__ __launch_bounds__(256) void geom_kernel(
    const float* __restrict__ pred_pts,   // [B,Q,P,3]
    const float* __restrict__ tgt_pts,    // [B,T,M,3]
    const int*   __restrict__ src_idx,    // [B,T]
    float*       __restrict__ per_patch)  // [N]
{
    __shared__ float4   s_tgt[Mm];        // 8 KB
    __shared__ float4   s_src[128];       // 2 KB (padded)
    __shared__ unsigned s_amin[Mm];       // 2 KB: per-m min over p (as uint)
    __shared__ float    s_bpart[8][128];  // 4 KB: per-chunk per-p partial mins
    __shared__ float    red[4];
    const int n   = blockIdx.x;
    const int tid = threadIdx.x;
    const int b   = n >> 7;               // n / T
    const int q   = src_idx[n];
    const float* sp = pred_pts + (size_t)(b * Qq + q) * (Pp * 3);
    const float* tp = tgt_pts  + (size_t)n * (Mm * 3);

    // Stage tgt: 512 pts x 3 floats = 768 float2; thread repacks 2 points.
    {
        const float2* tp2 = (const float2*)tp;
        const float2 a = tp2[3*tid], c2 = tp2[3*tid+1], e = tp2[3*tid+2];
        s_tgt[2*tid]   = make_float4(a.x, a.y, c2.x, 0.f);
        s_tgt[2*tid+1] = make_float4(c2.y, e.x, e.y, 0.f);
    }
    // Stage src: threads 0..49 repack 2 points each; 100..127 write sentinels.
    if (tid < 50) {
        const float2* sp2 = (const float2*)sp;
        const float2 a = sp2[3*tid], c2 = sp2[3*tid+1], e = sp2[3*tid+2];
        s_src[2*tid]   = make_float4(a.x, a.y, c2.x, 0.f);
        s_src[2*tid+1] = make_float4(c2.y, e.x, e.y, 0.f);
    } else if (tid >= 100 && tid < 128) {
        s_src[tid] = make_float4(5e18f, 5e18f, 5e18f, 0.f);
    }
    // Init per-m min array (uint encoding of FLT_MAX).
    *(uint2*)&s_amin[2*tid] = make_uint2(0x7f7fffffu, 0x7f7fffffu);
    __syncthreads();

    const int g = tid & 31;
    const int c = tid >> 5;               // m-chunk 0..7
    const int mbase = c << 6;
    const float4 s0 = s_src[4*g+0], s1 = s_src[4*g+1],
                 s2 = s_src[4*g+2], s3 = s_src[4*g+3];
    float mn0 = 3.4e38f, mn1 = 3.4e38f, mn2 = 3.4e38f, mn3 = 3.4e38f;

    #pragma unroll 4
    for (int j = 0; j < 64; ++j) {
        const int m = mbase + ((j + g) & 63);   // rotate: distinct addr per lane
        const float4 t = s_tgt[m];
        float dx, dy, dz;
        dx = s0.x - t.x; dy = s0.y - t.y; dz = s0.z - t.z;
        const float d0 = fmaf(dx, dx, fmaf(dy, dy, dz * dz));
        dx = s1.x - t.x; dy = s1.y - t.y; dz = s1.z - t.z;
        const float d1 = fmaf(dx, dx, fmaf(dy, dy, dz * dz));
        dx = s2.x - t.x; dy = s2.y - t.y; dz = s2.z - t.z;
        const float d2 = fmaf(dx, dx, fmaf(dy, dy, dz * dz));
        dx = s3.x - t.x; dy = s3.y - t.y; dz = s3.z - t.z;
        const float d3 = fmaf(dx, dx, fmaf(dy, dy, dz * dz));
        mn0 = fminf(mn0, d0); mn1 = fminf(mn1, d1);
        mn2 = fminf(mn2, d2); mn3 = fminf(mn3, d3);
        const float pm = fminf(fminf(d0, d1), fminf(d2, d3));
        atomicMin(&s_amin[m], __float_as_uint(pm));   // nonneg: uint cmp == float cmp
    }

    // Per-p partials for this chunk -> LDS (contiguous 4 floats = one b128).
    *(float4*)&s_bpart[c][4*g] = make_float4(mn0, mn1, mn2, mn3);
    __syncthreads();

    float contrib;
    // Pass A: mean over m of min_p. Thread sums its 2 m-slots.
    {
        const uint2 u = *(const uint2*)&s_amin[2*tid];
        contrib = (__uint_as_float(u.x) + __uint_as_float(u.y)) * (1.0f / Mm);
    }
    // Pass B: combine the 8 chunk-partials; threads 0..99 own one p each.
    if (tid < Pp) {
        float mn = s_bpart[0][tid];
        #pragma unroll
        for (int cc = 1; cc < 8; ++cc) mn = fminf(mn, s_bpart[cc][tid]);
        contrib += 0.2f * mn * (1.0f / Pp);
    }

    const float tot = breduce256(contrib, red);
    if (tid == 0) per_patch[n] = tot * (1.0f / 1.2f);
}

// Single block: CE loss, accuracies, cardinality, and final geometry sum.
__global__ __launch_bounds__(256) void cls_kernel(
    const float* __restrict__ logits,     // [B,Q,2]
    const int*   __restrict__ src_idx,    // [B,T]
    const float* __restrict__ per_patch,  // [N]
    float*       __restrict__ out)        // [5]
{
    __shared__ unsigned char matched[Bq * Qq];
    __shared__ int s_card[Bq];
    __shared__ float red[4];
    const int tid = threadIdx.x;
    for (int i = tid; i < Bq * Qq; i += 256) matched[i] = 0;
    if (tid < Bq) s_card[tid] = 0;
    __syncthreads();
    for (int i = tid; i < Nn; i += 256) {
        const int b = i >> 7;             // i / T
        matched[b * Qq + src_idx[i]] = 1;
    }
    __syncthreads();

    float sum_nll = 0.f, sum_wt = 0.f, cnt_overall = 0.f;
    #pragma unroll
    for (int k = 0; k < (Bq * Qq) / 256; ++k) {   // k == batch index b (Q==256)
        const int i = tid + k * 256;
        const float l0 = logits[2*i], l1 = logits[2*i + 1];
        const int   mt = matched[i];
        const float mx  = fmaxf(l0, l1);
        const float lse = mx + logf(expf(l0 - mx) + expf(l1 - mx));
        const float lt  = mt ? l0 : l1;           // logit of target class
        const float wt  = mt ? 1.0f : 0.1f;       // w[target], eos_coef = 0.1
        sum_nll += wt * (lse - lt);
        sum_wt  += wt;
        const int pred = (l0 >= l1) ? 0 : 1;      // argmax tie-break -> first
        const int c    = mt ? 0 : 1;
        cnt_overall += (pred == c) ? 1.f : 0.f;
        // cardinality: pred != last class  <=>  pred == 0
        const unsigned long long bal = __ballot(pred == 0);
        if ((tid & 63) == 0) atomicAdd(&s_card[k], (int)__popcll(bal));
    }

    float cnt_valid = 0.f;
    for (int i = tid; i < Nn; i += 256) {
        const int b = i >> 7;
        const int q = src_idx[i];
        const float l0 = logits[2*(b*Qq + q)], l1 = logits[2*(b*Qq + q) + 1];
        cnt_valid += (l0 >= l1) ? 1.f : 0.f;
    }

    float gsum = 0.f;
    for (int i = tid; i < Nn; i += 256) gsum += per_patch[i];

    const float t_nll = breduce256(sum_nll,     red);
    const float t_wt  = breduce256(sum_wt,      red);
    const float t_ov  = breduce256(cnt_overall, red);
    const float t_va  = breduce256(cnt_valid,   red);
    const float t_gs  = breduce256(gsum,        red);
    __syncthreads();

    if (tid == 0) {
        float cerr = 0.f;
        for (int b = 0; b < Bq; ++b) cerr += fabsf((float)s_card[b] - (float)Tt);
        out[0] = t_nll / t_wt;
        out[1] = 100.f * t_va / (float)Nn;
        out[2] = 100.f * t_ov / (float)(Bq * Qq);
        out[3] = cerr / (float)Bq;
        out[4] = t_gs / (float)Nn;
    }
}

extern "C" void kernel_launch(void* const* d_in, const int* in_sizes, int n_in,
                              void* d_out, int out_size, void* d_ws, size_t ws_size,
                              hipStream_t stream) {
    const float* logits   = (const float*)d_in[0];  // [B,Q,2]
    const float* pred_pts = (const float*)d_in[1];  // [B,Q,P,3]
    const float* tgt_pts  = (const float*)d_in[2];  // [B,T,M,3]
    const int*   src_idx  = (const int*)  d_in[3];  // [B,T]
    float* out       = (float*)d_out;               // 5 scalars
    float* per_patch = (float*)d_ws;                // 1024 floats scratch

    geom_kernel<<<Nn, 256, 0, stream>>>(pred_pts, tgt_pts, src_idx, per_patch);
    cls_kernel<<<1, 256, 0, stream>>>(logits, src_idx, per_patch, out);
}